// Round 9
// baseline (246.183 us; speedup 1.0000x reference)
//
#include <hip/hip_runtime.h>

// ParallelAttention router: q,k,v = x@Wq|Wk|Wv (16384x2048 @ 2048x64),
// out[t][i] = sum_j softmax_j(q_i*k_j) * v_j, fp32 in/out.
//
// Strategy: split-bf16 (hi/lo) MFMA GEMM fused with per-token softmax epilogue.
//   pack_w_kernel: lay out Wq|Wk|Wv as MFMA B-fragments (bf16 hi+lo) in d_ws.
//   router_kernel: 512 blocks x 512 thr (8 waves); block = 32 tokens; split-K
//     (waves 0-3 chunks 0..31, waves 4-7 chunks 32..63), wave = 32r x 48c.
//   A path: global_load_lds into double-buffered LDS (round 6: +21%), SWZ'd.
//   ROUND-8 CHANGE (schedule only, math bit-identical): __syncthreads drains
//   vmcnt(0) every chunk — no prefetch can fly across it (rounds 2/5/7 nulls).
//   Replaced with T3/T4 counted-vmcnt discipline (m218: +38-73%):
//     per chunk: vmcnt(7) -> s_barrier -> sched_barrier(0) -> compute
//                -> s_barrier -> issue A(c+2) gload_lds + B(c+2) asm loads.
//   Uniform 7 VMEM issues/chunk => vmcnt(7) at each top retires exactly
//   chunk-c's A+B (in-order retirement) leaving chunk-(c+1)'s 7 in flight;
//   flight spans ~2 chunk-walls, covering queued HBM latency. B loads are
//   inline-asm global_load_dwordx4 so the compiler can neither re-fuse them
//   (round 7) nor auto-insert drains; MFMA use is guarded by OUR vmcnt(7)
//   (asm-loaded regs get no compiler waitcnt) + sched_barrier(0) per rule #18.
//   Last chunk waits vmcnt(0). Race screen: absmax must stay 0.00390625.
//   (Round 8 bench was a broker/container failure — same burst pattern as
//   rounds 3-4, which later ran clean; source audited for barrier-uniformity
//   and vmcnt-accounting hang risks, none found; verbatim resubmit.)

typedef __bf16 bf16x8 __attribute__((ext_vector_type(8)));
typedef float f32x4  __attribute__((ext_vector_type(4)));

#define NTOK   16384
#define HDIM   2048
#define NCHUNK 64              // total K chunks of 32
#define KCH    32              // chunks per K-half (per wave group)
#define CH_STRIDE (12 * 2 * 512)  // bf16 elems per chunk in bfrag

// LDS A-tile swizzle: slot kq' of row r holds global k-group kq'^(r&7).
#define SWZ(row, kq) ((kq) ^ ((row) & 7))

#define GLOAD_LDS16(g, l)                                                      \
  __builtin_amdgcn_global_load_lds(                                            \
      (const __attribute__((address_space(1))) void*)(g),                      \
      (__attribute__((address_space(3))) void*)(l), 16, 0, 0)

#define WAITV7 asm volatile("s_waitcnt vmcnt(7)" ::: "memory")
#define WAITV0 asm volatile("s_waitcnt vmcnt(0)" ::: "memory")
#define SBAR   __builtin_amdgcn_s_barrier()
#define SCHEDB __builtin_amdgcn_sched_barrier(0)

// bfrag layout: [chunk 0..63][tile 0..11][hi=0/lo=1][lane 0..63][j 0..7]
// element = W_cat[k = chunk*32 + (lane>>4)*8 + j][n = tile*16 + (lane&15)]
// where W_cat cols: 0-63 = Wq, 64-127 = Wk, 128-191 = Wv.
__global__ void pack_w_kernel(const float* __restrict__ Wq,
                              const float* __restrict__ Wk,
                              const float* __restrict__ Wv,
                              __bf16* __restrict__ bfrag)
{
  int u = blockIdx.x * blockDim.x + threadIdx.x;   // (chunk, tile, lane)
  if (u >= NCHUNK * 12 * 64) return;
  int l  = u & 63;
  int tn = (u >> 6) % 12;
  int c  = u / (12 * 64);
  int n  = tn * 16 + (l & 15);
  int kb = c * 32 + ((l >> 4) << 3);
  const float* W = (n < 64) ? Wq : (n < 128) ? Wk : Wv;
  int nn = n & 63;
  bf16x8 hi, lo;
#pragma unroll
  for (int j = 0; j < 8; ++j) {
    float f = W[(size_t)(kb + j) * 64 + nn];
    __bf16 h = (__bf16)f;              // RNE
    hi[j] = h;
    lo[j] = (__bf16)(f - (float)h);    // residual
  }
  size_t base = (size_t)(c * 12 + tn) * 1024 + (size_t)l * 8;
  *(bf16x8*)(bfrag + base)       = hi;
  *(bf16x8*)(bfrag + base + 512) = lo;
}

// B fragments of chunk (cc) -> register set S, via inline-asm loads the
// compiler cannot re-schedule or auto-wait on. Byte offsets: tile t hi at
// t*2048, lo at t*2048+1024; 13-bit imm caps at 4095 so tiles 0-1 use base,
// tile 2 uses base+4096B.
#define ASMLOADB(S, cc)                                                        \
  {                                                                            \
    const __bf16* nbp  = bp + (size_t)(cc) * CH_STRIDE;                        \
    const __bf16* nbp4 = nbp + 2048;                                           \
    asm volatile("global_load_dwordx4 %0, %1, off"                             \
                 : "=&v"(S##h[0]) : "v"(nbp)  : "memory");                     \
    asm volatile("global_load_dwordx4 %0, %1, off offset:1024"                 \
                 : "=&v"(S##l[0]) : "v"(nbp)  : "memory");                     \
    asm volatile("global_load_dwordx4 %0, %1, off offset:2048"                 \
                 : "=&v"(S##h[1]) : "v"(nbp)  : "memory");                     \
    asm volatile("global_load_dwordx4 %0, %1, off offset:3072"                 \
                 : "=&v"(S##l[1]) : "v"(nbp)  : "memory");                     \
    asm volatile("global_load_dwordx4 %0, %1, off"                             \
                 : "=&v"(S##h[2]) : "v"(nbp4) : "memory");                     \
    asm volatile("global_load_dwordx4 %0, %1, off offset:1024"                 \
                 : "=&v"(S##l[2]) : "v"(nbp4) : "memory");                     \
  }

// Compute one chunk from LDS buffer `ab` with B register set S. Verbatim
// round-6 math (A swizzled reads, hi/lo split, 18 MFMA).
#define COMPUTE(ab, S)                                                         \
  {                                                                            \
    const int r0 = mr, r1 = 16 + mr;                                           \
    float4 A[4];                                                               \
    A[0] = *(const float4*)&(ab)[r0 * 32 + SWZ(r0, 2 * quad)     * 4];         \
    A[1] = *(const float4*)&(ab)[r0 * 32 + SWZ(r0, 2 * quad + 1) * 4];         \
    A[2] = *(const float4*)&(ab)[r1 * 32 + SWZ(r1, 2 * quad)     * 4];         \
    A[3] = *(const float4*)&(ab)[r1 * 32 + SWZ(r1, 2 * quad + 1) * 4];         \
    bf16x8 ah[2], al[2];                                                       \
    _Pragma("unroll")                                                          \
    for (int i = 0; i < 2; ++i) {                                              \
      float av[8] = {A[2*i].x, A[2*i].y, A[2*i].z, A[2*i].w,                   \
                     A[2*i+1].x, A[2*i+1].y, A[2*i+1].z, A[2*i+1].w};          \
      _Pragma("unroll")                                                        \
      for (int j = 0; j < 8; ++j) {                                            \
        __bf16 h = (__bf16)av[j];                                              \
        ah[i][j] = h;                                                          \
        al[i][j] = (__bf16)(av[j] - (float)h);                                 \
      }                                                                        \
    }                                                                          \
    _Pragma("unroll")                                                          \
    for (int i = 0; i < 2; ++i)                                                \
      _Pragma("unroll")                                                        \
      for (int t = 0; t < 3; ++t) {                                            \
        acc[i][t] = __builtin_amdgcn_mfma_f32_16x16x32_bf16(ah[i], S##h[t], acc[i][t], 0, 0, 0); \
        acc[i][t] = __builtin_amdgcn_mfma_f32_16x16x32_bf16(al[i], S##h[t], acc[i][t], 0, 0, 0); \
        acc[i][t] = __builtin_amdgcn_mfma_f32_16x16x32_bf16(ah[i], S##l[t], acc[i][t], 0, 0, 0); \
      }                                                                        \
  }

__global__ __launch_bounds__(512, 4) void router_kernel(
    const float* __restrict__ x,
    const __bf16* __restrict__ bfrag,
    float* __restrict__ out)
{
  const int tok0 = blockIdx.x * 32;
  const int w    = threadIdx.x >> 6;   // wave 0..7
  const int lane = threadIdx.x & 63;
  const int kh   = w >> 2;             // K-half: chunks [KCH*kh, KCH*kh+KCH)
  const int wc   = w & 3;              // col group: cols [48*wc, 48*wc+48)
  const int mr   = lane & 15;
  const int quad = lane >> 4;

  __shared__ float qkv[2][32 * 196];   // [K-half][32 tokens x 192 (+4 pad)]
  __shared__ float bufA[2][2][1024];   // [K-half][dbuf][32 rows x 32 k, SWZ'd]

  // --- A staging (global_load_lds): thread u' = tid&255 covers its half's
  // 4KB chunk tile. Row = u'>>3, LDS slot = u'&7; the slot CONTAINS global
  // k-group SWZ(row, slot). Wave-uniform LDS base + lane*16 (HW semantics).
  const int su   = threadIdx.x & 255;
  const int srow = su >> 3;            // 0..31
  const int skq  = su & 7;             // LDS 16B-slot within row
  const float* aSrc = x + (size_t)(tok0 + srow) * HDIM + kh * 1024
                        + SWZ(srow, skq) * 4;
  float* aDst0 = &bufA[kh][0][(w & 3) * 256];   // wave-uniform
  float* aDst1 = &bufA[kh][1][(w & 3) * 256];

  // B: L2-resident bfrag (MFMA-fragment packed), loaded via inline asm.
  const __bf16* bp = bfrag + (size_t)(kh * KCH) * CH_STRIDE
                           + (size_t)(3 * wc) * 1024 + (size_t)lane * 8;

  f32x4 acc[2][3];
#pragma unroll
  for (int i = 0; i < 2; ++i)
#pragma unroll
    for (int t = 0; t < 3; ++t)
      acc[i][t] = (f32x4){0.f, 0.f, 0.f, 0.f};

  // B register double-sets (asm-written; static indexing only — rule #20).
  bf16x8 B0h[3], B0l[3], B1h[3], B1l[3];

  // prologue: depth-2 issue, 14 VMEM ops in flight, no drain.
  GLOAD_LDS16(aSrc, aDst0);
  ASMLOADB(B0, 0)
  GLOAD_LDS16(aSrc + 32, aDst1);
  ASMLOADB(B1, 1)

  for (int c = 0; c < KCH; c += 2) {
    // ---- chunk c (even): buf0, set B0 ----
    WAITV7;                    // A(c),B(c) retired; A(c+1),B(c+1) in flight
    SBAR;                      // cross-wave: all A(c) quarters in LDS
    SCHEDB;                    // rule #18: nothing hoists above the wait
    COMPUTE(bufA[kh][0], B0)
    SBAR;                      // all waves done reading buf0
    if (c + 2 < KCH) {
      GLOAD_LDS16(aSrc + (c + 2) * 32, aDst0);
      ASMLOADB(B0, c + 2)
    }
    // ---- chunk c+1 (odd): buf1, set B1 ----
    if (c + 1 < KCH - 1) { WAITV7; } else { WAITV0; }
    SBAR;
    SCHEDB;
    COMPUTE(bufA[kh][1], B1)
    SBAR;
    if (c + 3 < KCH) {
      GLOAD_LDS16(aSrc + (c + 3) * 32, aDst1);
      ASMLOADB(B1, c + 3)
    }
  }

  // C/D layout (m89-verified): col = lane&15, row = (lane>>4)*4 + reg
#pragma unroll
  for (int i = 0; i < 2; ++i)
#pragma unroll
    for (int t = 0; t < 3; ++t) {
      int col = wc * 48 + t * 16 + mr;
      int row = i * 16 + quad * 4;
#pragma unroll
      for (int r = 0; r < 4; ++r)
        qkv[kh][(row + r) * 196 + col] = acc[i][t][r];
    }
  __syncthreads();

  // softmax epilogue: 16 threads per token, 4 outputs each; q/k/v are the
  // sum of the two K-half partials (fp32 add — order-only numerics change).
  // No max-subtraction needed: |q_i*k_j| <~ 26, exp2(26*1.44) well inside fp32.
  const int tt = threadIdx.x >> 4;     // token 0..31
  const int g  = threadIdx.x & 15;     // output group
  const float* q0 = qkv[0] + tt * 196;
  const float* q1 = qkv[1] + tt * 196;
  float qs[4], lsum[4], osum[4];
#pragma unroll
  for (int ii = 0; ii < 4; ++ii) {
    qs[ii]   = (q0[g * 4 + ii] + q1[g * 4 + ii]) * 1.44269504f;   // log2(e)
    lsum[ii] = 0.f;
    osum[ii] = 0.f;
  }
  for (int j = 0; j < 64; ++j) {
    float kj = q0[64 + j]  + q1[64 + j];
    float vj = q0[128 + j] + q1[128 + j];
#pragma unroll
    for (int ii = 0; ii < 4; ++ii) {
      float e = __builtin_amdgcn_exp2f(qs[ii] * kj);   // v_exp_f32
      lsum[ii] += e;
      osum[ii] = fmaf(e, vj, osum[ii]);
    }
  }
  float4 r0v;
  r0v.x = osum[0] / lsum[0]; r0v.y = osum[1] / lsum[1];
  r0v.z = osum[2] / lsum[2]; r0v.w = osum[3] / lsum[3];
  float* op = out + (size_t)(tok0 + tt) * 64 + g * 4;
  *(float4*)op = r0v;
}

extern "C" void kernel_launch(void* const* d_in, const int* in_sizes, int n_in,
                              void* d_out, int out_size, void* d_ws, size_t ws_size,
                              hipStream_t stream)
{
  const float* x  = (const float*)d_in[0];
  const float* Wq = (const float*)d_in[1];
  const float* Wk = (const float*)d_in[2];
  const float* Wv = (const float*)d_in[3];
  __bf16* bfrag   = (__bf16*)d_ws;          // needs 1.5 MiB of scratch
  float*  out     = (float*)d_out;

  pack_w_kernel<<<(NCHUNK * 12 * 64 + 255) / 256, 256, 0, stream>>>(Wq, Wk, Wv, bfrag);
  router_kernel<<<NTOK / 32, 512, 0, stream>>>(x, bfrag, out);
}

// Round 10
// 223.610 us; speedup vs baseline: 1.1009x; 1.1009x over previous
//
#include <hip/hip_runtime.h>

// ParallelAttention router: q,k,v = x@Wq|Wk|Wv (16384x2048 @ 2048x64),
// out[t][i] = sum_j softmax_j(q_i*k_j) * v_j, fp32 in/out.
//
// Strategy: split-bf16 (hi/lo) MFMA GEMM fused with per-token softmax epilogue.
//   router_kernel: 512 blocks x 512 thr (8 waves); block = 32 tokens; split-K
//     (waves 0-3 chunks 0..31, waves 4-7 chunks 32..63), wave = 32r x 48c.
//   ROUND-10 (consolidation; math bit-identical to rounds 6-9): iterate TWO
//   chunks per barrier-pair with counted vmcnt and depth-4 A staging:
//     [vmcnt(2) -> s_barrier -> sched_barrier -> COMPUTE(c) -> COMPUTE(c+1)
//      -> issue B(c+2),B(c+3) -> s_barrier -> issue A(c+4),A(c+5)]
//   Rationale: rounds 6/7/9 all plateau ~100us with all pipes <25% busy; the
//   residual cost model is per-sync-event latency JITTER (in-order vmcnt
//   retirement gates each wait on the slowest of 7 loads; each barrier on the
//   slowest of 8 waves). This halves wait events (16 vs 64), keeps barrier
//   count = round-6's 32, doubles compute per sync (36 MFMA), and gives
//   A-loads ~2 iteration-walls of flight (issued end of iter c, needed top of
//   iter c+4). B register double-sets (48 VGPR) reloaded mid-iteration after
//   their last MFMA use (VMEM writeback >=250cy after issue makes WAR vs
//   in-flight MFMA operand reads safe — AITER's standard interleave pattern).
//   LDS: A-buffers (4x4KB x 2 halves = 32KB) aliased INSIDE qkv's 50KB (bufA
//   dead before first qkv write; separated by the final s_barrier).
//   vmcnt audit: steady-state top-of-iter outstanding = {B(c),B(c+1),A(c+2),
//   A(c+3)} = 14; keep newest 2 (A's) -> vmcnt(2); tail iter -> vmcnt(0).
//   Race screen: absmax must stay exactly 0.00390625.

typedef __bf16 bf16x8 __attribute__((ext_vector_type(8)));
typedef float f32x4  __attribute__((ext_vector_type(4)));

#define NTOK   16384
#define HDIM   2048
#define NCHUNK 64              // total K chunks of 32
#define KCH    32              // chunks per K-half (per wave group)
#define CH_STRIDE (12 * 2 * 512)  // bf16 elems per chunk in bfrag

// LDS A-tile swizzle: slot kq' of row r holds global k-group kq'^(r&7).
#define SWZ(row, kq) ((kq) ^ ((row) & 7))

#define GLOAD_LDS16(g, l)                                                      \
  __builtin_amdgcn_global_load_lds(                                            \
      (const __attribute__((address_space(1))) void*)(g),                      \
      (__attribute__((address_space(3))) void*)(l), 16, 0, 0)

#define WAITV2 asm volatile("s_waitcnt vmcnt(2)" ::: "memory")
#define WAITV0 asm volatile("s_waitcnt vmcnt(0)" ::: "memory")
#define SBAR   __builtin_amdgcn_s_barrier()
#define SCHEDB __builtin_amdgcn_sched_barrier(0)

// bfrag layout: [chunk 0..63][tile 0..11][hi=0/lo=1][lane 0..63][j 0..7]
// element = W_cat[k = chunk*32 + (lane>>4)*8 + j][n = tile*16 + (lane&15)]
// where W_cat cols: 0-63 = Wq, 64-127 = Wk, 128-191 = Wv.
__global__ void pack_w_kernel(const float* __restrict__ Wq,
                              const float* __restrict__ Wk,
                              const float* __restrict__ Wv,
                              __bf16* __restrict__ bfrag)
{
  int u = blockIdx.x * blockDim.x + threadIdx.x;   // (chunk, tile, lane)
  if (u >= NCHUNK * 12 * 64) return;
  int l  = u & 63;
  int tn = (u >> 6) % 12;
  int c  = u / (12 * 64);
  int n  = tn * 16 + (l & 15);
  int kb = c * 32 + ((l >> 4) << 3);
  const float* W = (n < 64) ? Wq : (n < 128) ? Wk : Wv;
  int nn = n & 63;
  bf16x8 hi, lo;
#pragma unroll
  for (int j = 0; j < 8; ++j) {
    float f = W[(size_t)(kb + j) * 64 + nn];
    __bf16 h = (__bf16)f;              // RNE
    hi[j] = h;
    lo[j] = (__bf16)(f - (float)h);    // residual
  }
  size_t base = (size_t)(c * 12 + tn) * 1024 + (size_t)l * 8;
  *(bf16x8*)(bfrag + base)       = hi;
  *(bf16x8*)(bfrag + base + 512) = lo;
}

// B fragments of chunk (cc) -> register set S, via inline-asm loads the
// compiler cannot re-schedule or auto-wait on. Byte offsets: tile t hi at
// t*2048, lo at t*2048+1024; 13-bit imm caps at 4095 so tiles 0-1 use base,
// tile 2 uses base+4096B.
#define ASMLOADB(S, cc)                                                        \
  {                                                                            \
    const __bf16* nbp  = bp + (size_t)(cc) * CH_STRIDE;                        \
    const __bf16* nbp4 = nbp + 2048;                                           \
    asm volatile("global_load_dwordx4 %0, %1, off"                             \
                 : "=&v"(S##h[0]) : "v"(nbp)  : "memory");                     \
    asm volatile("global_load_dwordx4 %0, %1, off offset:1024"                 \
                 : "=&v"(S##l[0]) : "v"(nbp)  : "memory");                     \
    asm volatile("global_load_dwordx4 %0, %1, off offset:2048"                 \
                 : "=&v"(S##h[1]) : "v"(nbp)  : "memory");                     \
    asm volatile("global_load_dwordx4 %0, %1, off offset:3072"                 \
                 : "=&v"(S##l[1]) : "v"(nbp)  : "memory");                     \
    asm volatile("global_load_dwordx4 %0, %1, off"                             \
                 : "=&v"(S##h[2]) : "v"(nbp4) : "memory");                     \
    asm volatile("global_load_dwordx4 %0, %1, off offset:1024"                 \
                 : "=&v"(S##l[2]) : "v"(nbp4) : "memory");                     \
  }

// Compute one chunk from LDS buffer `ab` with B register set S. Verbatim
// round-6 math (A swizzled reads, hi/lo split, 18 MFMA).
#define COMPUTE(ab, S)                                                         \
  {                                                                            \
    const int r0 = mr, r1 = 16 + mr;                                           \
    float4 A[4];                                                               \
    A[0] = *(const float4*)&(ab)[r0 * 32 + SWZ(r0, 2 * quad)     * 4];         \
    A[1] = *(const float4*)&(ab)[r0 * 32 + SWZ(r0, 2 * quad + 1) * 4];         \
    A[2] = *(const float4*)&(ab)[r1 * 32 + SWZ(r1, 2 * quad)     * 4];         \
    A[3] = *(const float4*)&(ab)[r1 * 32 + SWZ(r1, 2 * quad + 1) * 4];         \
    bf16x8 ah[2], al[2];                                                       \
    _Pragma("unroll")                                                          \
    for (int i = 0; i < 2; ++i) {                                              \
      float av[8] = {A[2*i].x, A[2*i].y, A[2*i].z, A[2*i].w,                   \
                     A[2*i+1].x, A[2*i+1].y, A[2*i+1].z, A[2*i+1].w};          \
      _Pragma("unroll")                                                        \
      for (int j = 0; j < 8; ++j) {                                            \
        __bf16 h = (__bf16)av[j];                                              \
        ah[i][j] = h;                                                          \
        al[i][j] = (__bf16)(av[j] - (float)h);                                 \
      }                                                                        \
    }                                                                          \
    _Pragma("unroll")                                                          \
    for (int i = 0; i < 2; ++i)                                                \
      _Pragma("unroll")                                                        \
      for (int t = 0; t < 3; ++t) {                                            \
        acc[i][t] = __builtin_amdgcn_mfma_f32_16x16x32_bf16(ah[i], S##h[t], acc[i][t], 0, 0, 0); \
        acc[i][t] = __builtin_amdgcn_mfma_f32_16x16x32_bf16(al[i], S##h[t], acc[i][t], 0, 0, 0); \
        acc[i][t] = __builtin_amdgcn_mfma_f32_16x16x32_bf16(ah[i], S##l[t], acc[i][t], 0, 0, 0); \
      }                                                                        \
  }

__global__ __launch_bounds__(512, 4) void router_kernel(
    const float* __restrict__ x,
    const __bf16* __restrict__ bfrag,
    float* __restrict__ out)
{
  const int tok0 = blockIdx.x * 32;
  const int w    = threadIdx.x >> 6;   // wave 0..7
  const int lane = threadIdx.x & 63;
  const int kh   = w >> 2;             // K-half: chunks [KCH*kh, KCH*kh+KCH)
  const int wc   = w & 3;              // col group: cols [48*wc, 48*wc+48)
  const int mr   = lane & 15;
  const int quad = lane >> 4;

  // 50 KB shared: during K-loop, smem[kh][b*1024 .. +1023] are the 4 A-dbuf
  // tiles (b = chunk&3); after the final K-loop barrier the same storage is
  // qkv[kh][32*196] for the softmax epilogue (bufA dead by then).
  __shared__ float smem[2][32 * 196];

  // --- A staging (global_load_lds): thread u' = tid&255 covers its half's
  // 4KB chunk tile. Row = u'>>3, LDS slot = u'&7; the slot CONTAINS global
  // k-group SWZ(row, slot). Wave-uniform LDS base + lane*16 (HW semantics).
  const int su   = threadIdx.x & 255;
  const int srow = su >> 3;            // 0..31
  const int skq  = su & 7;             // LDS 16B-slot within row
  const float* aSrc = x + (size_t)(tok0 + srow) * HDIM + kh * 1024
                        + SWZ(srow, skq) * 4;
#define ABUF(b)  (&smem[kh][(b) * 1024])
#define ADST(b)  (&smem[kh][(b) * 1024 + (w & 3) * 256])   // wave-uniform

  // B: L2-resident bfrag (MFMA-fragment packed), loaded via inline asm.
  const __bf16* bp = bfrag + (size_t)(kh * KCH) * CH_STRIDE
                           + (size_t)(3 * wc) * 1024 + (size_t)lane * 8;

  f32x4 acc[2][3];
#pragma unroll
  for (int i = 0; i < 2; ++i)
#pragma unroll
    for (int t = 0; t < 3; ++t)
      acc[i][t] = (f32x4){0.f, 0.f, 0.f, 0.f};

  // B register double-sets (asm-written; static indexing only — rule #20).
  bf16x8 B0h[3], B0l[3], B1h[3], B1l[3];

  // prologue: B(0),B(1) + A(0..3): 16 VMEM ops, no drain.
  ASMLOADB(B0, 0)
  ASMLOADB(B1, 1)
  GLOAD_LDS16(aSrc + 0 * 32, ADST(0));
  GLOAD_LDS16(aSrc + 1 * 32, ADST(1));
  GLOAD_LDS16(aSrc + 2 * 32, ADST(2));
  GLOAD_LDS16(aSrc + 3 * 32, ADST(3));

  for (int c = 0; c < KCH; c += 2) {
    // top-of-iteration wait: retire A(c),A(c+1) (LDS) + B(c),B(c+1) (regs);
    // keep A(c+2),A(c+3) in flight (they're the 2 newest issues).
    if (c + 2 < KCH) { WAITV2; } else { WAITV0; }
    SBAR;                      // cross-wave: A(c),A(c+1) visible in LDS
    SCHEDB;                    // rule #18: nothing hoists above the wait

    COMPUTE(ABUF(c & 3),       B0)
    COMPUTE(ABUF((c + 1) & 3), B1)

    // reload B sets for iteration c+2 (last MFMA use of B0/B1 is >=250cy
    // before any VMEM writeback can land — WAR-safe).
    if (c + 2 < KCH) ASMLOADB(B0, c + 2)
    if (c + 3 < KCH) ASMLOADB(B1, c + 3)

    SBAR;                      // all waves done reading bufs (c&3),(c+1&3)
    if (c + 4 < KCH) GLOAD_LDS16(aSrc + (c + 4) * 32, ADST((c + 4) & 3));
    if (c + 5 < KCH) GLOAD_LDS16(aSrc + (c + 5) * 32, ADST((c + 5) & 3));
  }

  // K-loop done; final SBAR above separates last bufA read from qkv writes.
  // C/D layout (m89-verified): col = lane&15, row = (lane>>4)*4 + reg
#pragma unroll
  for (int i = 0; i < 2; ++i)
#pragma unroll
    for (int t = 0; t < 3; ++t) {
      int col = wc * 48 + t * 16 + mr;
      int row = i * 16 + quad * 4;
#pragma unroll
      for (int r = 0; r < 4; ++r)
        smem[kh][(row + r) * 196 + col] = acc[i][t][r];
    }
  __syncthreads();

  // softmax epilogue: 16 threads per token, 4 outputs each; q/k/v are the
  // sum of the two K-half partials (fp32 add — order-only numerics change).
  // No max-subtraction needed: |q_i*k_j| <~ 26, exp2(26*1.44) well inside fp32.
  const int tt = threadIdx.x >> 4;     // token 0..31
  const int g  = threadIdx.x & 15;     // output group
  const float* q0 = &smem[0][tt * 196];
  const float* q1 = &smem[1][tt * 196];
  float qs[4], lsum[4], osum[4];
#pragma unroll
  for (int ii = 0; ii < 4; ++ii) {
    qs[ii]   = (q0[g * 4 + ii] + q1[g * 4 + ii]) * 1.44269504f;   // log2(e)
    lsum[ii] = 0.f;
    osum[ii] = 0.f;
  }
  for (int j = 0; j < 64; ++j) {
    float kj = q0[64 + j]  + q1[64 + j];
    float vj = q0[128 + j] + q1[128 + j];
#pragma unroll
    for (int ii = 0; ii < 4; ++ii) {
      float e = __builtin_amdgcn_exp2f(qs[ii] * kj);   // v_exp_f32
      lsum[ii] += e;
      osum[ii] = fmaf(e, vj, osum[ii]);
    }
  }
  float4 r0v;
  r0v.x = osum[0] / lsum[0]; r0v.y = osum[1] / lsum[1];
  r0v.z = osum[2] / lsum[2]; r0v.w = osum[3] / lsum[3];
  float* op = out + (size_t)(tok0 + tt) * 64 + g * 4;
  *(float4*)op = r0v;
}

extern "C" void kernel_launch(void* const* d_in, const int* in_sizes, int n_in,
                              void* d_out, int out_size, void* d_ws, size_t ws_size,
                              hipStream_t stream)
{
  const float* x  = (const float*)d_in[0];
  const float* Wq = (const float*)d_in[1];
  const float* Wk = (const float*)d_in[2];
  const float* Wv = (const float*)d_in[3];
  __bf16* bfrag   = (__bf16*)d_ws;          // needs 1.5 MiB of scratch
  float*  out     = (float*)d_out;

  pack_w_kernel<<<(NCHUNK * 12 * 64 + 255) / 256, 256, 0, stream>>>(Wq, Wk, Wv, bfrag);
  router_kernel<<<NTOK / 32, 512, 0, stream>>>(x, bfrag, out);
}